// Round 3
// baseline (227.735 us; speedup 1.0000x reference)
//
#include <hip/hip_runtime.h>

// Net: x[B,2] -> fc1(2->9)+ELU -> 19 x (9->9)+ELU -> fc21(9->2) -> log_softmax
// B = 2097152. Round 3: chain the whole net through v_mfma_f32_16x16x16_f16.
// (Round 2 failed to compile: cvt_pkrtz returns __fp16 vector; use scalar
//  (_Float16) converts and let the compiler pack.)
//
// Key layout identity for 16x16x16 MFMA:
//   C/D:  lane L holds rows (L>>4)*4+reg     of col (L&15)
//   B:    lane L holds k  = (L>>4)*4+j       of col (L&15)
// => layer l's D converts IN-LANE (ELU + cvt) into layer l+1's B fragment.
//
// Bias trick: pad K to 16; row k=9 of the activation matrix is constant 1.0,
// col k=9 of each padded weight holds the bias. Rows 10..15 are zero (padded
// weight rows/cols zero), so garbage never propagates.
//
// log2e fold (setup kernel, fp32-exact):
//   layer0:  W' = log2e*W1, b' = log2e*b1     (input x is raw)
//   mid:     W' = Wmid,     b' = log2e*bmid   (input already carries log2e)
//   layer20: W' = ln2*W21,  b' = b21          (output = true logits)
// so pre-activations d = log2e * (Wh+b) and
//   scaled-ELU(d) = max(d, fma(exp2(min(d,0)), log2e, -log2e))   [4 VALU ops]

typedef _Float16 half4 __attribute__((ext_vector_type(4)));
typedef float float4v __attribute__((ext_vector_type(4)));

constexpr int H   = 9;
constexpr int NL  = 21;    // fc1 + 19 mid + fc21
constexpr int TPW = 8;     // batch tiles (of 16 rows) per wave
constexpr int BLK = 256;

__global__ void build_frags(const float* __restrict__ W1, const float* __restrict__ b1,
                            const float* __restrict__ Wmid, const float* __restrict__ bmid,
                            const float* __restrict__ W21, const float* __restrict__ b21,
                            _Float16* __restrict__ ws) {
    const float LOG2E = 1.4426950408889634f;
    const float LN2   = 0.6931471805599453f;
    int l = blockIdx.x;        // 0..20
    int p = threadIdx.x;       // 0..63  (lane position)
    int m = p & 15;            // A row (output neuron)
    int g = p >> 4;            // lane group
    for (int j = 0; j < 4; ++j) {
        int k = g * 4 + j;     // A col (input index)
        float v = 0.0f;
        if (l == 0) {
            if (m < H && k < 2)       v = LOG2E * W1[m * 2 + k];
            else if (m < H && k == 9) v = LOG2E * b1[m];
        } else if (l <= 19) {
            int li = l - 1;
            if (m < H && k < H)       v = Wmid[li * 81 + m * 9 + k];
            else if (m < H && k == 9) v = LOG2E * bmid[li * 9 + m];
        } else {
            if (m < 2 && k < H)       v = LN2 * W21[m * 9 + k];
            else if (m < 2 && k == 9) v = b21[m];
        }
        ws[l * 256 + p * 4 + j] = (_Float16)v;
    }
}

__global__ __launch_bounds__(BLK) void mlp_mfma(const float* __restrict__ x,
                                                const _Float16* __restrict__ ws,
                                                float* __restrict__ out) {
    const float LOG2E = 1.4426950408889634f;
    const int lane = threadIdx.x & 63;
    const int wave = (blockIdx.x * BLK + threadIdx.x) >> 6;
    const int col  = lane & 15;
    const int grp  = lane >> 4;

    // Per-lane A fragments for all 21 layers (2 VGPRs each), coalesced 8B/lane.
    half4 A[NL];
    const half4* wsv = (const half4*)ws;
    #pragma unroll
    for (int l = 0; l < NL; ++l) A[l] = wsv[l * 64 + lane];

    #pragma unroll 1
    for (int t = 0; t < TPW; ++t) {
        const long long tile = (long long)wave * TPW + t;
        const long long row  = tile * 16 + col;

        // Build B fragment for layer 0: rows 0,1 = x (only group 0 holds k=0..3),
        // row 9 = 1.0 (group 2, j=1), everything else 0.
        float2 xv = ((const float2*)x)[row];   // groups duplicate; L1 absorbs
        half4 b;
        b[0] = (_Float16)0.f; b[1] = (_Float16)0.f;
        b[2] = (_Float16)0.f; b[3] = (_Float16)0.f;
        if (grp == 0) { b[0] = (_Float16)xv.x; b[1] = (_Float16)xv.y; }
        if (grp == 2) { b[1] = (_Float16)1.0f; }

        float4v d;
        #pragma unroll
        for (int l = 0; l < NL; ++l) {
            d = __builtin_amdgcn_mfma_f32_16x16x16f16(A[l], b, (float4v){0.f, 0.f, 0.f, 0.f}, 0, 0, 0);
            if (l == NL - 1) break;
            // scaled ELU: h = max(d, log2e*exp2(min(d,0)) - log2e), 4 ops/elem
            float e;
            e = __builtin_amdgcn_exp2f(fminf(d[0], 0.f));
            b[0] = (_Float16)fmaxf(d[0], fmaf(e, LOG2E, -LOG2E));
            e = __builtin_amdgcn_exp2f(fminf(d[1], 0.f));
            b[1] = (_Float16)fmaxf(d[1], fmaf(e, LOG2E, -LOG2E));
            e = __builtin_amdgcn_exp2f(fminf(d[2], 0.f));
            b[2] = (_Float16)fmaxf(d[2], fmaf(e, LOG2E, -LOG2E));
            e = __builtin_amdgcn_exp2f(fminf(d[3], 0.f));
            b[3] = (_Float16)fmaxf(d[3], fmaf(e, LOG2E, -LOG2E));
            // re-inject the constant-1 bias row (k=9 -> group 2, j=1);
            // rows 9..15 of d are exactly 0 there, so this is the only fix-up.
            if (grp == 2) b[1] = (_Float16)1.0f;
        }

        // d rows 0,1 (group 0, regs 0,1) are the true logits for batch col.
        if (lane < 16) {
            float l0 = d[0], l1 = d[1];
            float m  = fmaxf(l0, l1);
            float e0 = __expf(l0 - m);
            float e1 = __expf(l1 - m);
            float lse = m + __logf(e0 + e1);
            ((float2*)out)[row] = make_float2(l0 - lse, l1 - lse);
        }
    }
}

extern "C" void kernel_launch(void* const* d_in, const int* in_sizes, int n_in,
                              void* d_out, int out_size, void* d_ws, size_t ws_size,
                              hipStream_t stream) {
    const float* x    = (const float*)d_in[0];
    const float* W1   = (const float*)d_in[1];
    const float* b1   = (const float*)d_in[2];
    const float* Wmid = (const float*)d_in[3];
    const float* bmid = (const float*)d_in[4];
    const float* W21  = (const float*)d_in[5];
    const float* b21  = (const float*)d_in[6];
    float* out = (float*)d_out;
    _Float16* ws = (_Float16*)d_ws;   // 21*256 halves = 10.5 KB

    build_frags<<<NL, 64, 0, stream>>>(W1, b1, Wmid, bmid, W21, b21, ws);

    const int nrows = in_sizes[0] / 2;           // 2097152
    const int tiles = nrows / 16;                // 131072
    const int waves = tiles / TPW;               // 16384
    const int blocks = waves * 64 / BLK;         // 4096
    mlp_mfma<<<blocks, BLK, 0, stream>>>(x, ws, out);
}

// Round 4
// 190.501 us; speedup vs baseline: 1.1955x; 1.1955x over previous
//
#include <hip/hip_runtime.h>

// Net: x[B,2] -> fc1(2->9)+ELU -> 19 x (9->9)+ELU -> fc21(9->2) -> log_softmax
// B = 2097152. Round 4: MFMA chain (round 3) + packed-fp16 activation path.
// Round-3 postmortem: VALUBusy 95%, MfmaUtil 11% -> per-layer ELU/cvt VALU ops
// are the bottleneck (~23 insts/layer: scalar cvt+pack, f32 min/exp/fma/max).
// This round: cvt_pkrtz (correct __fp16 vector type) + v_pk_min/fma/max_f16 +
// v_exp_f16, bias row reinjected with a single v_or_b32 -> ~15 insts/layer.
//
// Layout identity (16x16x16 f16 MFMA):
//   C/D: lane L holds rows (L>>4)*4+reg of col (L&15)
//   B:   lane L holds k  = (L>>4)*4+j   of col (L&15)
// => layer l's D converts IN-LANE into layer l+1's B fragment.
// Bias trick: K slot 9 = constant 1.0 (group 2, j=1 -> high half of b-reg 0);
// weight col 9 holds the bias. A rows 9..15 are zero => D rows 9..15 exactly
// +0.0, and scaled-ELU(+0)=+0 bit-exact, so OR-ing 0x3C00<<16 injects 1.0h.
//
// log2e fold (setup kernel, fp32-exact):
//   layer0:  W' = log2e*W1, b' = log2e*b1
//   mid:     W' = Wmid,     b' = log2e*bmid
//   layer20: W' = ln2*W21,  b' = b21          (output = true logits)
// scaled-ELU(d) = max(d, fma(exp2(min(d,0)), log2e, -log2e))  [packed fp16]

typedef _Float16 half4 __attribute__((ext_vector_type(4)));
typedef _Float16 h2 __attribute__((ext_vector_type(2)));
typedef __fp16 fp16x2 __attribute__((ext_vector_type(2)));
typedef float float4v __attribute__((ext_vector_type(4)));
typedef unsigned int uint2v __attribute__((ext_vector_type(2)));

extern "C" __device__ _Float16 __ocml_exp2_f16(_Float16);

constexpr int H   = 9;
constexpr int NL  = 21;    // fc1 + 19 mid + fc21
constexpr int TPW = 8;     // batch tiles (of 16 rows) per wave
constexpr int BLK = 256;

__global__ void build_frags(const float* __restrict__ W1, const float* __restrict__ b1,
                            const float* __restrict__ Wmid, const float* __restrict__ bmid,
                            const float* __restrict__ W21, const float* __restrict__ b21,
                            _Float16* __restrict__ ws) {
    const float LOG2E = 1.4426950408889634f;
    const float LN2   = 0.6931471805599453f;
    int l = blockIdx.x;        // 0..20
    int p = threadIdx.x;       // 0..63
    int m = p & 15;            // A row (output neuron)
    int g = p >> 4;            // lane group
    for (int j = 0; j < 4; ++j) {
        int k = g * 4 + j;     // A col (input index)
        float v = 0.0f;
        if (l == 0) {
            if (m < H && k < 2)       v = LOG2E * W1[m * 2 + k];
            else if (m < H && k == 9) v = LOG2E * b1[m];
        } else if (l <= 19) {
            int li = l - 1;
            if (m < H && k < H)       v = Wmid[li * 81 + m * 9 + k];
            else if (m < H && k == 9) v = LOG2E * bmid[li * 9 + m];
        } else {
            if (m < 2 && k < H)       v = LN2 * W21[m * 9 + k];
            else if (m < 2 && k == 9) v = b21[m];
        }
        ws[l * 256 + p * 4 + j] = (_Float16)v;
    }
}

// scaled ELU on 4 fp32 pre-acts -> packed half4 B-fragment (+ bias 1.0h via OR)
__device__ __forceinline__ half4 act_to_b(float4v d, unsigned bias_or) {
    const h2 Z  = {(_Float16)0.f, (_Float16)0.f};
    const h2 L  = {(_Float16)1.4426950408889634f, (_Float16)1.4426950408889634f};
    const h2 nL = {(_Float16)-1.4426950408889634f, (_Float16)-1.4426950408889634f};
    h2 p0 = __builtin_bit_cast(h2, __builtin_amdgcn_cvt_pkrtz(d[0], d[1]));
    h2 p1 = __builtin_bit_cast(h2, __builtin_amdgcn_cvt_pkrtz(d[2], d[3]));
    h2 t0 = __builtin_elementwise_min(p0, Z);
    h2 t1 = __builtin_elementwise_min(p1, Z);
    h2 e0, e1;
    e0[0] = __ocml_exp2_f16(t0[0]);
    e0[1] = __ocml_exp2_f16(t0[1]);
    e1[0] = __ocml_exp2_f16(t1[0]);
    e1[1] = __ocml_exp2_f16(t1[1]);
    h2 g0 = __builtin_elementwise_max(p0, __builtin_elementwise_fma(e0, L, nL));
    h2 g1 = __builtin_elementwise_max(p1, __builtin_elementwise_fma(e1, L, nL));
    uint2v u;
    u[0] = __builtin_bit_cast(unsigned, g0) | bias_or;
    u[1] = __builtin_bit_cast(unsigned, g1);
    return __builtin_bit_cast(half4, u);
}

// layer-0 B fragment: k rows 0,1 = x (group 0), k=9 = 1.0h (group 2 hi-half)
__device__ __forceinline__ half4 x_to_b(float2 xv, unsigned g0_sel, unsigned bias_or) {
    unsigned ux = __builtin_bit_cast(unsigned, __builtin_amdgcn_cvt_pkrtz(xv.x, xv.y));
    uint2v u;
    u[0] = (ux & g0_sel) | bias_or;
    u[1] = 0u;
    return __builtin_bit_cast(half4, u);
}

__device__ __forceinline__ void write_out(float4v d, float* __restrict__ out,
                                          long long row, int lane) {
    if (lane < 16) {
        float l0 = d[0], l1 = d[1];
        float m  = fmaxf(l0, l1);
        float e0 = __expf(l0 - m);
        float e1 = __expf(l1 - m);
        float lse = m + __logf(e0 + e1);
        ((float2*)out)[row] = make_float2(l0 - lse, l1 - lse);
    }
}

__global__ __launch_bounds__(BLK) void mlp_mfma(const float* __restrict__ x,
                                                const _Float16* __restrict__ ws,
                                                float* __restrict__ out) {
    const int lane = threadIdx.x & 63;
    const int wave = (blockIdx.x * BLK + threadIdx.x) >> 6;
    const int col  = lane & 15;
    const int grp  = lane >> 4;

    half4 A[NL];
    const half4* wsv = (const half4*)ws;
    #pragma unroll
    for (int l = 0; l < NL; ++l) A[l] = wsv[l * 64 + lane];

    const unsigned bias_or = (grp == 2) ? 0x3C000000u : 0u;  // 1.0h in hi half
    const unsigned g0_sel  = (grp == 0) ? 0xFFFFFFFFu : 0u;

    #pragma unroll 1
    for (int t = 0; t < TPW; t += 2) {
        const long long rowa = ((long long)wave * TPW + t) * 16 + col;
        const long long rowb = rowa + 16;

        float2 xa = ((const float2*)x)[rowa];
        float2 xb = ((const float2*)x)[rowb];
        half4 ba = x_to_b(xa, g0_sel, bias_or);
        half4 bb = x_to_b(xb, g0_sel, bias_or);

        float4v da, db;
        #pragma unroll
        for (int l = 0; l < NL; ++l) {
            da = __builtin_amdgcn_mfma_f32_16x16x16f16(A[l], ba, (float4v){0.f,0.f,0.f,0.f}, 0, 0, 0);
            db = __builtin_amdgcn_mfma_f32_16x16x16f16(A[l], bb, (float4v){0.f,0.f,0.f,0.f}, 0, 0, 0);
            if (l < NL - 1) {
                ba = act_to_b(da, bias_or);
                bb = act_to_b(db, bias_or);
            }
        }
        write_out(da, out, rowa, lane);
        write_out(db, out, rowb, lane);
    }
}

extern "C" void kernel_launch(void* const* d_in, const int* in_sizes, int n_in,
                              void* d_out, int out_size, void* d_ws, size_t ws_size,
                              hipStream_t stream) {
    const float* x    = (const float*)d_in[0];
    const float* W1   = (const float*)d_in[1];
    const float* b1   = (const float*)d_in[2];
    const float* Wmid = (const float*)d_in[3];
    const float* bmid = (const float*)d_in[4];
    const float* W21  = (const float*)d_in[5];
    const float* b21  = (const float*)d_in[6];
    float* out = (float*)d_out;
    _Float16* ws = (_Float16*)d_ws;   // 21*256 halves = 10.5 KB

    build_frags<<<NL, 64, 0, stream>>>(W1, b1, Wmid, bmid, W21, b21, ws);

    const int nrows = in_sizes[0] / 2;           // 2097152
    const int tiles = nrows / 16;                // 131072
    const int waves = tiles / TPW;               // 16384
    const int blocks = waves * 64 / BLK;         // 4096
    mlp_mfma<<<blocks, BLK, 0, stream>>>(x, ws, out);
}

// Round 5
// 179.110 us; speedup vs baseline: 1.2715x; 1.0636x over previous
//
#include <hip/hip_runtime.h>

// Net: x[B,2] -> fc1(2->9)+ELU -> 19 x (9->9)+ELU -> fc21(9->2) -> log_softmax
// B = 2097152. Round 5: 16x16x32 MFMA with relu/exp K-slot split.
//
// Identity: ELU(z) = relu(z) + exp2(min(L*z,0)) - 1   (L = log2e), valid for
// ALL z. The "-1" and scales are linear -> folded into next layer's A/bias.
// So the per-layer epilogue only computes relu(d) and e2m(d)=exp2(min(d,0))
// where d = L*z is the (scaled) pre-activation: NO pk_fma, NO final max.
//
// MFMA 16x16x32 f16 layouts (verified m89/m118-m122 lineage):
//   C/D: lane L holds rows (L>>4)*4+reg       of col (L&15)   [4 f32]
//   B:   lane L holds k  = (L>>4)*8+j (j=0..7) of col (L&15)   [8 f16]
// Slot map (g=lane>>4): j=0..2 -> relu of D regs 0..2; j=4..6 -> e2m of
// D regs 0..2; j=3,7 dead; k=24 (g=3,j=0) = bias slot (constant 1.0h).
//
// Neuron permutation: neuron i lives at matrix row p(i) in {0,1,2,4,5,6,8,9,10}
// (p(i)=i+i/3), so only D regs 0..2 carry data; D reg 3 rows {3,7,11,15} have
// zero A rows -> d[3] == +0.0 exactly -> 3 exps/layer instead of 4.
//
// Weight folding (build_frags, fp32-exact):
//   relu slots carry L*relu(z_prev), e2m slots carry e^min(z_prev,0):
//   mid   l: A[p(o)][krelu(i)] = W[o][i];  A[p(o)][kexp(i)] = L*W[o][i]
//            A[p(o)][24]      = L*(b[o] - sum_i W[o][i])
//   l=0:     A[p(o)][0,1]     = L*W1[o][:] ; A[p(o)][24] = L*b1[o]
//   l=20:    A[o][krelu(i)]   = ln2*W21[o][i]; A[o][kexp(i)] = W21[o][i]
//            A[o][24]         = b21[o] - sum_i W21[o][i]

typedef _Float16 half8 __attribute__((ext_vector_type(8)));
typedef _Float16 h2 __attribute__((ext_vector_type(2)));
typedef float float4v __attribute__((ext_vector_type(4)));
typedef unsigned int uint4v __attribute__((ext_vector_type(4)));

extern "C" __device__ _Float16 __ocml_exp2_f16(_Float16);

constexpr int H   = 9;
constexpr int NL  = 21;    // fc1 + 19 mid + fc21
constexpr int TPW = 8;     // batch tiles (of 16 rows) per wave
constexpr int BLK = 256;

__global__ void build_frags(const float* __restrict__ W1, const float* __restrict__ b1,
                            const float* __restrict__ Wmid, const float* __restrict__ bmid,
                            const float* __restrict__ W21, const float* __restrict__ b21,
                            _Float16* __restrict__ ws) {
    const float L   = 1.4426950408889634f;   // log2(e)
    const float LN2 = 0.6931471805599453f;
    int l    = blockIdx.x;      // 0..20
    int lane = threadIdx.x;     // 0..63
    int row  = lane & 15;       // A row
    int g    = lane >> 4;       // k group
    // output neuron at this row (rows {0,1,2,4,5,6,8,9,10}); row 12 = bias col target row? no: bias is a COLUMN; rows 11..15 unused.
    bool orow = ((row & 3) != 3) && (row < 12);
    int  o    = row - (row >> 2);           // inverse of p(i)=i+i/3
    for (int j = 0; j < 8; ++j) {
        int k = g * 8 + j;
        float v = 0.0f;
        if (l == 0) {
            if (orow && k < 2)        v = L * W1[o * 2 + k];
            else if (orow && k == 24) v = L * b1[o];
        } else if (l <= 19) {
            const float* W = Wmid + (l - 1) * 81;
            const float* b = bmid + (l - 1) * 9;
            if (orow) {
                if (j < 3 && g < 3) {                    // relu slot
                    int r_in = g * 4 + j;
                    int i = r_in - (r_in >> 2);
                    v = W[o * 9 + i];
                } else if (j >= 4 && j < 7 && g < 3) {   // e2m slot
                    int r_in = g * 4 + (j - 4);
                    int i = r_in - (r_in >> 2);
                    v = L * W[o * 9 + i];
                } else if (k == 24) {                    // bias slot
                    float s = 0.0f;
                    for (int i = 0; i < H; ++i) s += W[o * 9 + i];
                    v = L * (b[o] - s);
                }
            }
        } else {  // l == 20: logits, out neurons at rows 0,1
            if (row < 2) {
                if (j < 3 && g < 3) {
                    int r_in = g * 4 + j;
                    int i = r_in - (r_in >> 2);
                    v = LN2 * W21[row * 9 + i];
                } else if (j >= 4 && j < 7 && g < 3) {
                    int r_in = g * 4 + (j - 4);
                    int i = r_in - (r_in >> 2);
                    v = W21[row * 9 + i];
                } else if (k == 24) {
                    float s = 0.0f;
                    for (int i = 0; i < H; ++i) s += W21[row * 9 + i];
                    v = b21[row] - s;
                }
            }
        }
        ws[l * 512 + lane * 8 + j] = (_Float16)v;
    }
}

// d (4 f32, d[3]==+0) -> next-layer B fragment {relu01, relu2x, e01, e2x}
__device__ __forceinline__ half8 act_to_b(float4v d, unsigned bias_or) {
    const h2 Z = {(_Float16)0.f, (_Float16)0.f};
    h2 p01 = __builtin_bit_cast(h2, __builtin_amdgcn_cvt_pkrtz(d[0], d[1]));
    h2 p2x = __builtin_bit_cast(h2, __builtin_amdgcn_cvt_pkrtz(d[2], d[3]));
    h2 r01 = __builtin_elementwise_max(p01, Z);
    h2 r2x = __builtin_elementwise_max(p2x, Z);
    h2 t01 = __builtin_elementwise_min(p01, Z);
    h2 t2x = __builtin_elementwise_min(p2x, Z);
    h2 e01;
    e01[0] = __ocml_exp2_f16(t01[0]);
    e01[1] = __ocml_exp2_f16(t01[1]);
    h2 e2x = t2x;                       // hi half dead (=0), keep as-is
    e2x[0] = __ocml_exp2_f16(t2x[0]);
    uint4v u;
    u[0] = __builtin_bit_cast(unsigned, r01) | bias_or;  // bias 1.0h @ g3 j0
    u[1] = __builtin_bit_cast(unsigned, r2x);
    u[2] = __builtin_bit_cast(unsigned, e01);
    u[3] = __builtin_bit_cast(unsigned, e2x);
    return __builtin_bit_cast(half8, u);
}

// layer-0 B: k=0,1 = x (group 0 only), k=24 = 1.0h, rest 0
__device__ __forceinline__ half8 x_to_b(float2 xv, unsigned g0_sel, unsigned bias_or) {
    unsigned ux = __builtin_bit_cast(unsigned, __builtin_amdgcn_cvt_pkrtz(xv.x, xv.y));
    uint4v u;
    u[0] = (ux & g0_sel) | bias_or;
    u[1] = 0u; u[2] = 0u; u[3] = 0u;
    return __builtin_bit_cast(half8, u);
}

__device__ __forceinline__ void write_out(float4v d, float* __restrict__ out,
                                          long long row, int lane) {
    if (lane < 16) {
        float l0 = d[0], l1 = d[1];
        float m  = fmaxf(l0, l1);
        float e0 = __expf(l0 - m);
        float e1 = __expf(l1 - m);
        float lse = m + __logf(e0 + e1);
        ((float2*)out)[row] = make_float2(l0 - lse, l1 - lse);
    }
}

__global__ __launch_bounds__(BLK) void mlp_mfma(const float* __restrict__ x,
                                                const _Float16* __restrict__ ws,
                                                float* __restrict__ out) {
    const int lane = threadIdx.x & 63;
    const int wave = (blockIdx.x * BLK + threadIdx.x) >> 6;
    const int grp  = lane >> 4;
    const int col  = lane & 15;

    half8 A[NL];
    const half8* wsv = (const half8*)ws;
    #pragma unroll
    for (int l = 0; l < NL; ++l) A[l] = wsv[l * 64 + lane];

    const unsigned bias_or = (grp == 3) ? 0x00003C00u : 0u;  // 1.0h, lo half
    const unsigned g0_sel  = (grp == 0) ? 0xFFFFFFFFu : 0u;

    #pragma unroll 1
    for (int t = 0; t < TPW; t += 2) {
        const long long rowa = ((long long)wave * TPW + t) * 16 + col;
        const long long rowb = rowa + 16;

        float2 xa = ((const float2*)x)[rowa];
        float2 xb = ((const float2*)x)[rowb];
        half8 ba = x_to_b(xa, g0_sel, bias_or);
        half8 bb = x_to_b(xb, g0_sel, bias_or);

        float4v da, db;
        #pragma unroll
        for (int l = 0; l < NL; ++l) {
            da = __builtin_amdgcn_mfma_f32_16x16x32_f16(A[l], ba, (float4v){0.f,0.f,0.f,0.f}, 0, 0, 0);
            db = __builtin_amdgcn_mfma_f32_16x16x32_f16(A[l], bb, (float4v){0.f,0.f,0.f,0.f}, 0, 0, 0);
            if (l < NL - 1) {
                ba = act_to_b(da, bias_or);
                bb = act_to_b(db, bias_or);
            }
        }
        write_out(da, out, rowa, lane);
        write_out(db, out, rowb, lane);
    }
}

extern "C" void kernel_launch(void* const* d_in, const int* in_sizes, int n_in,
                              void* d_out, int out_size, void* d_ws, size_t ws_size,
                              hipStream_t stream) {
    const float* x    = (const float*)d_in[0];
    const float* W1   = (const float*)d_in[1];
    const float* b1   = (const float*)d_in[2];
    const float* Wmid = (const float*)d_in[3];
    const float* bmid = (const float*)d_in[4];
    const float* W21  = (const float*)d_in[5];
    const float* b21  = (const float*)d_in[6];
    float* out = (float*)d_out;
    _Float16* ws = (_Float16*)d_ws;   // 21*512 halves = 21.5 KB

    build_frags<<<NL, 64, 0, stream>>>(W1, b1, Wmid, bmid, W21, b21, ws);

    const int nrows = in_sizes[0] / 2;           // 2097152
    const int tiles = nrows / 16;                // 131072
    const int waves = tiles / TPW;               // 16384
    const int blocks = waves * 64 / BLK;         // 4096
    mlp_mfma<<<blocks, BLK, 0, stream>>>(x, ws, out);
}

// Round 6
// 176.052 us; speedup vs baseline: 1.2936x; 1.0174x over previous
//
#include <hip/hip_runtime.h>

// Net: x[B,2] -> fc1(2->9)+ELU -> 19 x (9->9)+ELU -> fc21(9->2) -> log_softmax
// B = 2097152. Round 6: round-5 structure (16x16x32 MFMA, relu/exp K-split)
// + 4-way tile ILP + wave-batched log-softmax epilogue via ds_bpermute
// + softplus-form lse (2 trans) + 32-bit indexing.
//
// MFMA 16x16x32 f16 layouts:
//   C/D: lane L holds rows (L>>4)*4+reg        of col (L&15)   [4 f32]
//   B:   lane L holds k  = (L>>4)*8+j (j=0..7) of col (L&15)   [8 f16]
// Slot map (g=lane>>4): j=0..2 relu of D regs 0..2; j=4..6 e2m of D regs
// 0..2; j=3,7 dead (A cols zero); k=24 (g=3,j=0) = bias slot (1.0h).
// Neurons permuted to rows {0,1,2,4,5,6,8,9,10} so D reg 3 rows are all-zero
// A rows -> d[3]==+0.0 -> only 3 exps/layer. Rows 12..15 also zero, so the
// bias OR at g3 (d[0]=row12=+0 -> relu=+0) injects exactly 1.0h.
//
// ELU identity: ELU(z) = relu(z) + exp2(min(L*z,0)) - 1, scales/-1 folded
// into the next layer's weights/bias (see build_frags).

typedef _Float16 half8 __attribute__((ext_vector_type(8)));
typedef _Float16 h2 __attribute__((ext_vector_type(2)));
typedef float float4v __attribute__((ext_vector_type(4)));
typedef unsigned int uint4v __attribute__((ext_vector_type(4)));

extern "C" __device__ _Float16 __ocml_exp2_f16(_Float16);

constexpr int H   = 9;
constexpr int NL  = 21;    // fc1 + 19 mid + fc21
constexpr int TPW = 8;     // batch tiles (of 16 rows) per wave
constexpr int BLK = 256;

__global__ void build_frags(const float* __restrict__ W1, const float* __restrict__ b1,
                            const float* __restrict__ Wmid, const float* __restrict__ bmid,
                            const float* __restrict__ W21, const float* __restrict__ b21,
                            _Float16* __restrict__ ws) {
    const float L   = 1.4426950408889634f;   // log2(e)
    const float LN2 = 0.6931471805599453f;
    int l    = blockIdx.x;      // 0..20
    int lane = threadIdx.x;     // 0..63
    int row  = lane & 15;       // A row
    int g    = lane >> 4;       // k group
    bool orow = ((row & 3) != 3) && (row < 12);   // rows {0,1,2,4,5,6,8,9,10}
    int  o    = row - (row >> 2);                 // neuron index at this row
    for (int j = 0; j < 8; ++j) {
        int k = g * 8 + j;
        float v = 0.0f;
        if (l == 0) {
            if (orow && k < 2)        v = L * W1[o * 2 + k];
            else if (orow && k == 24) v = L * b1[o];
        } else if (l <= 19) {
            const float* W = Wmid + (l - 1) * 81;
            const float* b = bmid + (l - 1) * 9;
            if (orow) {
                if (j < 3 && g < 3) {                    // relu slot
                    int r_in = g * 4 + j;
                    int i = r_in - (r_in >> 2);
                    v = W[o * 9 + i];
                } else if (j >= 4 && j < 7 && g < 3) {   // e2m slot
                    int r_in = g * 4 + (j - 4);
                    int i = r_in - (r_in >> 2);
                    v = L * W[o * 9 + i];
                } else if (k == 24) {                    // bias slot
                    float s = 0.0f;
                    for (int i = 0; i < H; ++i) s += W[o * 9 + i];
                    v = L * (b[o] - s);
                }
            }
        } else {  // l == 20: logits at rows 0,1
            if (row < 2) {
                if (j < 3 && g < 3) {
                    int r_in = g * 4 + j;
                    int i = r_in - (r_in >> 2);
                    v = LN2 * W21[row * 9 + i];
                } else if (j >= 4 && j < 7 && g < 3) {
                    int r_in = g * 4 + (j - 4);
                    int i = r_in - (r_in >> 2);
                    v = W21[row * 9 + i];
                } else if (k == 24) {
                    float s = 0.0f;
                    for (int i = 0; i < H; ++i) s += W21[row * 9 + i];
                    v = b21[row] - s;
                }
            }
        }
        ws[l * 512 + lane * 8 + j] = (_Float16)v;
    }
}

// d (4 f32, d[3]==+0) -> next-layer B fragment {relu01, relu2x, e01, e2x}
__device__ __forceinline__ half8 act_to_b(float4v d, unsigned bias_or) {
    const h2 Z = {(_Float16)0.f, (_Float16)0.f};
    h2 p01 = __builtin_bit_cast(h2, __builtin_amdgcn_cvt_pkrtz(d[0], d[1]));
    h2 p2x = __builtin_bit_cast(h2, __builtin_amdgcn_cvt_pkrtz(d[2], d[3]));
    h2 r01 = __builtin_elementwise_max(p01, Z);
    h2 r2x = __builtin_elementwise_max(p2x, Z);
    h2 t01 = __builtin_elementwise_min(p01, Z);
    h2 t2x = __builtin_elementwise_min(p2x, Z);
    h2 e01;
    e01[0] = __ocml_exp2_f16(t01[0]);
    e01[1] = __ocml_exp2_f16(t01[1]);
    h2 e2x = t2x;                       // hi half dead (A col zero)
    e2x[0] = __ocml_exp2_f16(t2x[0]);
    uint4v u;
    u[0] = __builtin_bit_cast(unsigned, r01) | bias_or;  // bias 1.0h @ g3 j0
    u[1] = __builtin_bit_cast(unsigned, r2x);
    u[2] = __builtin_bit_cast(unsigned, e01);
    u[3] = __builtin_bit_cast(unsigned, e2x);
    return __builtin_bit_cast(half8, u);
}

// layer-0 B: k=0,1 = x (group 0 only), k=24 = 1.0h, rest 0
__device__ __forceinline__ half8 x_to_b(float2 xv, unsigned g0_sel, unsigned bias_or) {
    unsigned ux = __builtin_bit_cast(unsigned, __builtin_amdgcn_cvt_pkrtz(xv.x, xv.y));
    uint4v u;
    u[0] = (ux & g0_sel) | bias_or;
    u[1] = 0u; u[2] = 0u; u[3] = 0u;
    return __builtin_bit_cast(half8, u);
}

__device__ __forceinline__ float bperm(int byte_idx, float v) {
    return __builtin_bit_cast(float,
        __builtin_amdgcn_ds_bpermute(byte_idx, __builtin_bit_cast(int, v)));
}

__global__ __launch_bounds__(BLK) void mlp_mfma(const float* __restrict__ x,
                                                const _Float16* __restrict__ ws,
                                                float* __restrict__ out) {
    const int lane = threadIdx.x & 63;
    const int wave = (blockIdx.x * BLK + threadIdx.x) >> 6;
    const int grp  = lane >> 4;
    const int col  = lane & 15;

    half8 A[NL];
    const half8* wsv = (const half8*)ws;
    #pragma unroll
    for (int l = 0; l < NL; ++l) A[l] = wsv[l * 64 + lane];

    const unsigned bias_or = (grp == 3) ? 0x00003C00u : 0u;  // 1.0h, lo half
    const unsigned g0_sel  = (grp == 0) ? 0xFFFFFFFFu : 0u;
    const float4v ZV = {0.f, 0.f, 0.f, 0.f};
    const float NLOG2E = -1.4426950408889634f;
    const float LN2f   = 0.6931471805599453f;

    #pragma unroll 1
    for (int t = 0; t < TPW; t += 4) {
        const int tile0 = wave * TPW + t;           // < 131072, 32-bit safe

        half8 bf[4];
        #pragma unroll
        for (int k = 0; k < 4; ++k) {
            float2 xv = ((const float2*)x)[((tile0 + k) << 4) + col];
            bf[k] = x_to_b(xv, g0_sel, bias_or);
        }

        float4v dd[4];
        #pragma unroll
        for (int l = 0; l < NL; ++l) {
            #pragma unroll
            for (int k = 0; k < 4; ++k)
                dd[k] = __builtin_amdgcn_mfma_f32_16x16x32_f16(A[l], bf[k], ZV, 0, 0, 0);
            if (l < NL - 1) {
                #pragma unroll
                for (int k = 0; k < 4; ++k)
                    bf[k] = act_to_b(dd[k], bias_or);
            }
        }

        // Wave-batched log-softmax: lane-group g handles tile (tile0+g).
        // Logits live in lanes 0..15 (rows 0,1 = regs 0,1); bpermute spreads
        // batch-row m's logits of tile k to lane 16k+m, then ONE full-wave
        // softplus and ONE fully-coalesced 512B float2 store.
        const int bidx = col << 2;
        float a0 = bperm(bidx, dd[0][0]), a1 = bperm(bidx, dd[0][1]);
        float b0 = bperm(bidx, dd[1][0]), b1 = bperm(bidx, dd[1][1]);
        float c0 = bperm(bidx, dd[2][0]), c1 = bperm(bidx, dd[2][1]);
        float d0 = bperm(bidx, dd[3][0]), d1 = bperm(bidx, dd[3][1]);
        float l0 = (grp == 0) ? a0 : (grp == 1) ? b0 : (grp == 2) ? c0 : d0;
        float l1 = (grp == 0) ? a1 : (grp == 1) ? b1 : (grp == 2) ? c1 : d1;

        float mx  = fmaxf(l0, l1);
        float ad  = fabsf(l0 - l1);
        float e   = __builtin_amdgcn_exp2f(NLOG2E * ad);
        float lg  = __builtin_amdgcn_logf(1.0f + e);     // log2(1+e)
        float lse = fmaf(LN2f, lg, mx);
        ((float2*)out)[(tile0 << 4) + lane] = make_float2(l0 - lse, l1 - lse);
    }
}

extern "C" void kernel_launch(void* const* d_in, const int* in_sizes, int n_in,
                              void* d_out, int out_size, void* d_ws, size_t ws_size,
                              hipStream_t stream) {
    const float* x    = (const float*)d_in[0];
    const float* W1   = (const float*)d_in[1];
    const float* b1   = (const float*)d_in[2];
    const float* Wmid = (const float*)d_in[3];
    const float* bmid = (const float*)d_in[4];
    const float* W21  = (const float*)d_in[5];
    const float* b21  = (const float*)d_in[6];
    float* out = (float*)d_out;
    _Float16* ws = (_Float16*)d_ws;   // 21*512 halves = 21.5 KB

    build_frags<<<NL, 64, 0, stream>>>(W1, b1, Wmid, bmid, W21, b21, ws);

    const int nrows = in_sizes[0] / 2;           // 2097152
    const int tiles = nrows / 16;                // 131072
    const int waves = tiles / TPW;               // 16384
    const int blocks = waves * 64 / BLK;         // 4096
    mlp_mfma<<<blocks, BLK, 0, stream>>>(x, ws, out);
}